// Round 4
// baseline (238.588 us; speedup 1.0000x reference)
//
#include <hip/hip_runtime.h>
#include <hip/hip_bf16.h>
#include <math.h>

// (B,S,D,H) = (2,2048,1024,16), DK=64
#define B_ 2
#define S_ 2048
#define D_ 1024
#define H_ 16
#define DK_ 64

#define ROPE_C 0.4152410118609203f   // log2(10000)/32
#define LOG2E 1.4426950408889634f

typedef float f4 __attribute__((ext_vector_type(4)));
typedef float f16x __attribute__((ext_vector_type(16)));
typedef short s8 __attribute__((ext_vector_type(8)));

__device__ __forceinline__ ushort f2b(float f) {
  union { float f; uint u; } v; v.f = f;
  uint u = v.u + 0x7fffu + ((v.u >> 16) & 1u);
  return (ushort)(u >> 16);
}

__device__ __forceinline__ float b2f(ushort u) {
  union { uint u; float f; } v; v.u = ((uint)u) << 16;
  return v.f;
}

// packed f32x2 -> bf16x2 (T12: no builtin on gfx950; lo = src0)
__device__ __forceinline__ uint cvtpk(float a, float b) {
  uint r;
  asm("v_cvt_pk_bf16_f32 %0, %1, %2" : "=v"(r) : "v"(a), "v"(b));
  return r;
}

// async global->LDS DMA, 16 B per lane. LDS dest = wave-uniform base + lane*16.
__device__ __forceinline__ void async16(const ushort* g, ushort* l) {
  __builtin_amdgcn_global_load_lds(
      (const __attribute__((address_space(1))) uint*)g,
      (__attribute__((address_space(3))) uint*)l, 16, 0, 0);
}

// ---------------------------------------------------------------------------
// Fused prep: blocks 0..6143 = fp32->bf16 convert of q/k/v (8 elems/thread);
// blocks 6144..7167 = W transpose (4 matrices, 16x16 tiles of 64x64).
// ---------------------------------------------------------------------------
__global__ __launch_bounds__(256) void prep_all(
    const float* __restrict__ q_in, const float* __restrict__ k_in,
    const float* __restrict__ v_in,
    ushort* __restrict__ Xbq, ushort* __restrict__ Xbk, ushort* __restrict__ Xbv,
    const float* __restrict__ Wq, const float* __restrict__ Wk,
    const float* __restrict__ Wv, const float* __restrict__ Wo,
    ushort* __restrict__ Wtqkv, ushort* __restrict__ Wto) {
  __shared__ ushort T[64][65];
  const int bid = blockIdx.x, t = threadIdx.x;
  if (bid < 6144) {
    const int m = bid >> 11;  // /2048
    const float* in = (m == 0) ? q_in : (m == 1) ? k_in : v_in;
    ushort* out = (m == 0) ? Xbq : (m == 1) ? Xbk : Xbv;
    int idx = ((bid & 2047) * 256 + t) * 8;
    float4 a = *(const float4*)&in[idx];
    float4 b = *(const float4*)&in[idx + 4];
    ushort tmp[8] = {f2b(a.x), f2b(a.y), f2b(a.z), f2b(a.w),
                     f2b(b.x), f2b(b.y), f2b(b.z), f2b(b.w)};
    *(uint4*)&out[idx] = *(uint4*)tmp;
  } else {
    const int tb = bid - 6144;
    const int m = tb >> 8;
    const float* W = (m == 0) ? Wq : (m == 1) ? Wk : (m == 2) ? Wv : Wo;
    ushort* Wt = (m == 3) ? Wto : Wtqkv + (size_t)m * 1024 * 1024;
    const int k0 = (tb & 15) * 64, n0 = ((tb >> 4) & 15) * 64;
    #pragma unroll
    for (int i = 0; i < 16; ++i) {
      int e = t + i * 256, r = e >> 6, c = e & 63;
      T[c][r] = f2b(W[(size_t)(k0 + r) * D_ + n0 + c]);
    }
    __syncthreads();
    #pragma unroll
    for (int i = 0; i < 16; ++i) {
      int e = t + i * 256, r = e >> 6, c = e & 63;
      Wt[(size_t)(n0 + r) * D_ + k0 + c] = T[r][c];
    }
  }
}

// ---------------------------------------------------------------------------
// MFMA GEMM v2: BM=BN=128, BK=32, 4 waves 2x2, 4x4 frags/wave.
// Double-buffered global_load_lds staging, one barrier per K-step.
// MODE 0: dense bf16 [4096][1024] per matrix (bias only).
// MODE 2: fp32 [M][N] + bias (final projection), direct stores.
// ---------------------------------------------------------------------------
template <int MODE>
__global__ __launch_bounds__(256) void gemm_mfma(
    const ushort* __restrict__ A0, const ushort* __restrict__ A1,
    const ushort* __restrict__ A2, const ushort* __restrict__ Bt,
    const float* __restrict__ bb0, const float* __restrict__ bb1,
    const float* __restrict__ bb2,
    ushort* __restrict__ oq, ushort* __restrict__ ok, ushort* __restrict__ ov,
    float* __restrict__ oo) {
  __shared__ ushort SM[16384];  // 32 KB: As[2][4096] | Bs[2][4096]
  ushort* Es = SM;              // MODE 0 epilogue [64][144]=9216, aliases K-loop bufs

  const int t = threadIdx.x, w = t >> 6, l = t & 63;
  const int m0 = blockIdx.x * 128, n0 = blockIdx.y * 128;
  const int wm = (w >> 1) * 64, wn = (w & 1) * 64;
  const int lm = l & 15, q4 = (l >> 4) * 4;
  const int hb = l >> 4;

  const ushort* A;
  const float* bias;
  int mat = 0;
  if constexpr (MODE == 0) {
    mat = n0 >> 10;
    A = (mat == 0) ? A0 : (mat == 1) ? A1 : A2;
    bias = (mat == 0) ? bb0 : (mat == 1) ? bb1 : bb2;
  } else {
    A = A0; bias = bb0;
  }

  const int srow = w * 32 + (l >> 2);
  const int pb = l & 3;
  const int lb = pb ^ (srow & 3);
  const ushort* gA = A + (size_t)(m0 + srow) * D_ + lb * 8;
  const ushort* gB = Bt + (size_t)(n0 + srow) * D_ + lb * 8;

#define GSTAGE(bf, kk)                                   \
  {                                                      \
    ushort* lA = SM + (bf) * 4096 + w * 1024;            \
    ushort* lB = SM + 8192 + (bf) * 4096 + w * 1024;     \
    async16(gA + (kk), lA);                              \
    async16(gA + 16 * D_ + (kk), lA + 512);              \
    async16(gB + (kk), lB);                              \
    async16(gB + 16 * D_ + (kk), lB + 512);              \
  }

  f4 acc[4][4];
  #pragma unroll
  for (int i = 0; i < 4; ++i)
    #pragma unroll
    for (int j = 0; j < 4; ++j) acc[i][j] = (f4){0.f, 0.f, 0.f, 0.f};

  GSTAGE(0, 0);
  __syncthreads();

  for (int k0 = 0; k0 < D_; k0 += 32) {
    const int bf = (k0 >> 5) & 1;
    if (k0 + 32 < D_) GSTAGE(bf ^ 1, k0 + 32);
    const ushort* Asb = SM + bf * 4096;
    const ushort* Bsb = SM + 8192 + bf * 4096;
    s8 af[4], bfr[4];
    #pragma unroll
    for (int mt = 0; mt < 4; ++mt) {
      int ra = wm + mt * 16 + lm;
      af[mt] = *(const s8*)&Asb[ra * 32 + ((hb ^ (ra & 3)) << 3)];
    }
    #pragma unroll
    for (int nt = 0; nt < 4; ++nt) {
      int rb = wn + nt * 16 + lm;
      bfr[nt] = *(const s8*)&Bsb[rb * 32 + ((hb ^ (rb & 3)) << 3)];
    }
    __builtin_amdgcn_s_setprio(1);
    #pragma unroll
    for (int mt = 0; mt < 4; ++mt)
      #pragma unroll
      for (int nt = 0; nt < 4; ++nt)
        acc[mt][nt] = __builtin_amdgcn_mfma_f32_16x16x32_bf16(af[mt], bfr[nt], acc[mt][nt], 0, 0, 0);
    __builtin_amdgcn_s_setprio(0);
    __syncthreads();
  }

  // ---- epilogue ----
  if constexpr (MODE == 2) {
    #pragma unroll
    for (int nt = 0; nt < 4; ++nt) {
      int n = n0 + wn + nt * 16 + lm;
      float bv = bias[n];
      #pragma unroll
      for (int mt = 0; mt < 4; ++mt)
        #pragma unroll
        for (int r = 0; r < 4; ++r)
          oo[(size_t)(m0 + wm + mt * 16 + q4 + r) * D_ + n] = acc[mt][nt][r] + bv;
    }
  } else {
    ushort* dst = (mat == 0) ? oq : (mat == 1) ? ok : ov;
    const int nm0 = n0 & 1023;
    #pragma unroll
    for (int p = 0; p < 2; ++p) {
      if ((w >> 1) == p) {
        #pragma unroll
        for (int nt = 0; nt < 4; ++nt) {
          int col = wn + nt * 16 + lm;
          float bv = bias[nm0 + col];
          #pragma unroll
          for (int mt = 0; mt < 4; ++mt)
            #pragma unroll
            for (int r = 0; r < 4; ++r)
              Es[(mt * 16 + q4 + r) * 144 + col] = f2b(acc[mt][nt][r] + bv);
        }
      }
      __syncthreads();
      #pragma unroll
      for (int i = 0; i < 4; ++i) {
        int e = t + i * 256, row = e >> 4, ch = e & 15;
        *(uint4*)&dst[(size_t)(m0 + p * 64 + row) * D_ + nm0 + ch * 8] =
            *(const uint4*)&Es[row * 144 + ch * 8];
      }
      __syncthreads();
    }
  }
#undef GSTAGE
}

// ---------------------------------------------------------------------------
// RoPE + relayout pass (memory-bound). Grid (32 bh, 32 s-tiles), 256 thr.
// Q is pre-scaled by (1/sqrt(DK)) * LOG2E so attention works in exp2 domain.
// ---------------------------------------------------------------------------
__global__ __launch_bounds__(256) void rope_pass(
    const ushort* __restrict__ qtmp, const ushort* __restrict__ ktmp,
    const ushort* __restrict__ vtmp,
    ushort* __restrict__ qfb, ushort* __restrict__ kfb,
    ushort* __restrict__ vtb) {
  __shared__ ushort T[64][72];
  const int t = threadIdx.x;
  const int bh = blockIdx.x, st = blockIdx.y;
  const int b = bh >> 4, h = bh & 15;
  const int s0 = st * 64;
  const int r = t >> 2, c0 = (t & 3) * 16;
  const int s = s0 + r;

  float cs[16], sn[16];
  const float pos = (float)s;
  #pragma unroll
  for (int j = 0; j < 16; ++j) {
    float invf = exp2f(-(float)((c0 + j) & 31) * ROPE_C);
    __sincosf(pos * invf, &sn[j], &cs[j]);
  }

  const size_t src = ((size_t)(b * S_ + s)) * D_ + h * 64 + c0;
  const size_t dstqk = ((size_t)bh * S_ + s) * DK_ + c0;

  #pragma unroll
  for (int tensor = 0; tensor < 2; ++tensor) {
    const ushort* in = tensor ? ktmp : qtmp;
    ushort* out = tensor ? kfb : qfb;
    const float scale = tensor ? 1.f : 0.18033688011112042f;  // 0.125*LOG2E
    uint4 raw0 = *(const uint4*)&in[src];
    uint4 raw1 = *(const uint4*)&in[src + 8];
    ushort xr[16];
    *(uint4*)&xr[0] = raw0;
    *(uint4*)&xr[8] = raw1;
    float x[16];
    #pragma unroll
    for (int j = 0; j < 16; ++j) x[j] = b2f(xr[j]);
    ushort o[16];
    #pragma unroll
    for (int j = 0; j < 16; j += 2) {
      float e = x[j] * cs[j] - x[j + 1] * sn[j + 1];
      float d = x[j] * sn[j] + x[j + 1] * cs[j + 1];
      o[j] = f2b(e * scale);
      o[j + 1] = f2b(d * scale);
    }
    *(uint4*)&out[dstqk] = *(const uint4*)&o[0];
    *(uint4*)&out[dstqk + 8] = *(const uint4*)&o[8];
  }

  {
    uint4 raw0 = *(const uint4*)&vtmp[src];
    uint4 raw1 = *(const uint4*)&vtmp[src + 8];
    ushort xr[16];
    *(uint4*)&xr[0] = raw0;
    *(uint4*)&xr[8] = raw1;
    #pragma unroll
    for (int j = 0; j < 16; ++j) T[c0 + j][r] = xr[j];
    __syncthreads();
    const size_t dstv = ((size_t)bh * DK_ + r) * S_ + s0 + c0;
    *(uint4*)&vtb[dstv] = *(const uint4*)&T[r][c0];
    *(uint4*)&vtb[dstv + 8] = *(const uint4*)&T[r][c0 + 8];
  }
}

// ---------------------------------------------------------------------------
// MFMA flash attention v5: 32x32x16 MFMA (16 FLOP per LDS byte, 2x v4).
// 2 waves/block (128 thr), wave w owns q-rows [i0+32w, i0+32w+32).
// Scores via mfma(A=K, B=Q): C col = lane&31 = q (lane-local softmax rows,
// lanes l and l^32 hold complementary key halves -> 1 shfl_xor(32) merge).
// PV as O^T = mfma(A=V^T, B=P^T): C col = q again -> alpha/il all lane-local.
// P^T B-frag built IN REGISTERS (cvt_pk + 8 shfl_xor(32) + cndmask) - P never
// touches LDS. LDS = K/V double-buffer only (32 KB), v3's prefetch +
// single-barrier pipeline, XOR-8 swizzle with pre-swizzled DMA source.
// Grid (32 bh, 32 qt) LPT; 1024 blocks -> 4 blocks/CU, 8 waves/CU.
// ---------------------------------------------------------------------------
__global__ __launch_bounds__(128, 2) void attn_mfma(const ushort* __restrict__ qf,
                                                    const ushort* __restrict__ kf,
                                                    const ushort* __restrict__ vtf,
                                                    ushort* __restrict__ ctx) {
  __shared__ ushort Ks[2][4096];   // [buf][64 keys][64 dk], 8-blk XOR swizzled
  __shared__ ushort Vs[2][4096];   // [buf][64 d][64 keys], 8-blk XOR swizzled

  const int t = threadIdx.x, w = t >> 6, l = t & 63;
  const int bh = blockIdx.x, qt = 31 - (int)blockIdx.y;
  const int i0 = qt * 64;
  const int lo = l & 31, hi = l >> 5;
  const size_t base = (size_t)bh * S_ * DK_;
  const int b = bh >> 4, h = bh & 15;

  // ---- staging: wave0 -> K tile, wave1 -> V tile. 8 async16 each. ----
  const int sr = l >> 3, pbk = l & 7;
  const int swS = (pbk ^ sr) << 3;                    // pre-swizzled src block
  const ushort* gk = kf + base + (size_t)sr * DK_ + swS;
  const ushort* gv = vtf + base + (size_t)sr * S_ + swS;

#define STAGE(bf, j0)                                                      \
  if (w == 0) {                                                            \
    _Pragma("unroll")                                                      \
    for (int i = 0; i < 8; ++i)                                            \
      async16(gk + (size_t)((j0) + 8 * i) * DK_, &Ks[bf][i * 512]);        \
  } else {                                                                 \
    _Pragma("unroll")                                                      \
    for (int i = 0; i < 8; ++i)                                            \
      async16(gv + (size_t)(8 * i) * S_ + (j0), &Vs[bf][i * 512]);         \
  }

  // ---- Q B-frags (loop-invariant): col q = lo, k-dims 16s+8hi+e ----
  const ushort* qp = qf + base + (size_t)(i0 + w * 32 + lo) * DK_;
  s8 bq[4];
  #pragma unroll
  for (int s = 0; s < 4; ++s) bq[s] = *(const s8*)&qp[s * 16 + hi * 8];

  const int rsw = lo & 7;        // read-side swizzle (row&7)
  const int roff = lo * 64;      // row base in ushorts

  STAGE(0, 0);

  f16x O0, O1;
  #pragma unroll
  for (int r = 0; r < 16; ++r) { O0[r] = 0.f; O1[r] = 0.f; }
  float m_ = -1e30f, l_ = 0.f;   // softmax state for q = i0+32w+lo (exp2 dom)

  __syncthreads();

  for (int jt = 0; jt <= qt; ++jt) {
    const int cur = jt & 1;
    if (jt < qt) STAGE(cur ^ 1, (jt + 1) * 64);   // prefetch next tile
    const ushort* Kb = Ks[cur];
    const ushort* Vb = Vs[cur];

    // ---- S^T = K @ Q^T : tile0 keys 0-31 (s0), tile1 keys 32-63 (s1) ----
    f16x s0, s1;
    #pragma unroll
    for (int r = 0; r < 16; ++r) { s0[r] = 0.f; s1[r] = 0.f; }
    __builtin_amdgcn_s_setprio(1);
    #pragma unroll
    for (int s = 0; s < 4; ++s) {
      const int co = ((2 * s + hi) ^ rsw) << 3;
      s8 a0 = *(const s8*)&Kb[roff + co];
      s8 a1 = *(const s8*)&Kb[2048 + roff + co];
      s0 = __builtin_amdgcn_mfma_f32_32x32x16_bf16(a0, bq[s], s0, 0, 0, 0);
      s1 = __builtin_amdgcn_mfma_f32_32x32x16_bf16(a1, bq[s], s1, 0, 0, 0);
    }
    __builtin_amdgcn_s_setprio(0);

    if (jt == qt) {  // causal: key = 32t+8(r>>2)+4hi+(r&3) vs q = 32w+lo
      const int qr = 32 * w + lo;
      #pragma unroll
      for (int r = 0; r < 16; ++r) {
        const int kb0 = 8 * (r >> 2) + 4 * hi + (r & 3);
        if (kb0 > qr) s0[r] = -1e30f;
        if (kb0 + 32 > qr) s1[r] = -1e30f;
      }
    }

    // ---- row max: 31 local + 1 shfl_xor(32) ----
    float pm = s0[0];
    #pragma unroll
    for (int r = 1; r < 16; ++r) pm = fmaxf(pm, s0[r]);
    #pragma unroll
    for (int r = 0; r < 16; ++r) pm = fmaxf(pm, s1[r]);
    pm = fmaxf(pm, __shfl_xor(pm, 32));

    // ---- defer-max (T13) ----
    const bool stable = __all(pm <= m_ + 4.0f);
    float mn = m_;
    if (!stable) mn = fmaxf(m_, pm);

    // ---- exp (exp2 domain) + row sum ----
    #pragma unroll
    for (int r = 0; r < 16; ++r) {
      s0[r] = exp2f(s0[r] - mn);
      s1[r] = exp2f(s1[r] - mn);
    }
    float ps = s0[0];
    #pragma unroll
    for (int r = 1; r < 16; ++r) ps += s0[r];
    #pragma unroll
    for (int r = 0; r < 16; ++r) ps += s1[r];
    ps += __shfl_xor(ps, 32);

    if (stable) {
      l_ += ps;
    } else {
      const float alpha = exp2f(m_ - mn);   // lane-local, no broadcast
      m_ = mn;
      l_ = l_ * alpha + ps;
      #pragma unroll
      for (int r = 0; r < 16; ++r) { O0[r] *= alpha; O1[r] *= alpha; }
    }

    // ---- P^T B-frag in registers: pack, half-swap, select ----
    uint pk0[8], pk1[8];
    #pragma unroll
    for (int m = 0; m < 8; ++m) {
      pk0[m] = cvtpk(s0[2 * m], s0[2 * m + 1]);
      pk1[m] = cvtpk(s1[2 * m], s1[2 * m + 1]);
    }
    // pre-select send words: hi=0 sends pk[{2,3,6,7}], hi=1 sends pk[{0,1,4,5}]
    uint zz0[4], zz1[4];
    {
      uint z0[4], z1[4];
      z0[0] = hi ? pk0[0] : pk0[2];  z0[1] = hi ? pk0[1] : pk0[3];
      z0[2] = hi ? pk0[4] : pk0[6];  z0[3] = hi ? pk0[5] : pk0[7];
      z1[0] = hi ? pk1[0] : pk1[2];  z1[1] = hi ? pk1[1] : pk1[3];
      z1[2] = hi ? pk1[4] : pk1[6];  z1[3] = hi ? pk1[5] : pk1[7];
      #pragma unroll
      for (int c = 0; c < 4; ++c) {
        zz0[c] = __shfl_xor((int)z0[c], 32);
        zz1[c] = __shfl_xor((int)z1[c], 32);
      }
    }
    // bfrag[s] words j: j<2: hi? zz[t][2(s&1)+(j&1)] : pk[t][4(s&1)+(j&1)]
    //                   j>=2: hi? pk[t][4(s&1)+2+(j&1)] : zz[t][2(s&1)+(j&1)]
    uint bw[16];
    bw[0]  = hi ? zz0[0] : pk0[0];  bw[1]  = hi ? zz0[1] : pk0[1];
    bw[2]  = hi ? pk0[2] : zz0[0];  bw[3]  = hi ? pk0[3] : zz0[1];
    bw[4]  = hi ? zz0[2] : pk0[4];  bw[5]  = hi ? zz0[3] : pk0[5];
    bw[6]  = hi ? pk0[6] : zz0[2];  bw[7]  = hi ? pk0[7] : zz0[3];
    bw[8]  = hi ? zz1[0] : pk1[0];  bw[9]  = hi ? zz1[1] : pk1[1];
    bw[10] = hi ? pk1[2] : zz1[0];  bw[11] = hi ? pk1[3] : zz1[1];
    bw[12] = hi ? zz1[2] : pk1[4];  bw[13] = hi ? zz1[3] : pk1[5];
    bw[14] = hi ? pk1[6] : zz1[2];  bw[15] = hi ? pk1[7] : zz1[3];
    const s8* bfr = (const s8*)bw;

    // ---- PV: O^T = V^T @ P^T (C rows = d, cols = q) ----
    __builtin_amdgcn_s_setprio(1);
    #pragma unroll
    for (int s = 0; s < 4; ++s) {
      const int co = ((2 * s + hi) ^ rsw) << 3;
      s8 a0 = *(const s8*)&Vb[roff + co];
      s8 a1 = *(const s8*)&Vb[2048 + roff + co];
      O0 = __builtin_amdgcn_mfma_f32_32x32x16_bf16(a0, bfr[s], O0, 0, 0, 0);
      O1 = __builtin_amdgcn_mfma_f32_32x32x16_bf16(a1, bfr[s], O1, 0, 0, 0);
    }
    __builtin_amdgcn_s_setprio(0);

    // single barrier: prefetched tile visible + buf reuse protected.
    __syncthreads();
  }

  // ---- epilogue: scale by 1/l_ (lane-local), transpose via LDS (Ks[0]) ----
  {
    const float il = 1.f / l_;
    ushort* Ts = &Ks[0][0];
    const int q = w * 32 + lo;
    #pragma unroll
    for (int r = 0; r < 16; r += 2) {
      const int o = r >> 2;
      const int sub = (4 * hi + (r & 3)) * 2;            // byte within block
      uint v0 = cvtpk(O0[r] * il, O0[r + 1] * il);       // d = 8o+4hi+(r&3)
      uint v1 = cvtpk(O1[r] * il, O1[r + 1] * il);       // d = 32+...
      *(uint*)((char*)Ts + q * 128 + ((o ^ (q & 7)) << 4) + sub) = v0;
      *(uint*)((char*)Ts + q * 128 + (((4 + o) ^ (q & 7)) << 4) + sub) = v1;
    }
    __syncthreads();
    #pragma unroll
    for (int i = 0; i < 4; ++i) {
      int e = t + i * 128, row = e >> 3, ch = e & 7;
      int sg = i0 + row;
      *(uint4*)&ctx[((size_t)(b * S_ + sg)) * D_ + h * 64 + ch * 8] =
          *(const uint4*)((const char*)Ts + row * 128 + ((ch ^ (row & 7)) << 4));
    }
  }
#undef STAGE
}

// ---------------------------------------------------------------------------
extern "C" void kernel_launch(void* const* d_in, const int* in_sizes, int n_in,
                              void* d_out, int out_size, void* d_ws, size_t ws_size,
                              hipStream_t stream) {
  const float* q_in = (const float*)d_in[0];
  const float* k_in = (const float*)d_in[1];
  const float* v_in = (const float*)d_in[2];
  const float* Wq = (const float*)d_in[3];
  const float* bq = (const float*)d_in[4];
  const float* Wk = (const float*)d_in[5];
  const float* bk = (const float*)d_in[6];
  const float* Wv = (const float*)d_in[7];
  const float* bv = (const float*)d_in[8];
  const float* Wo = (const float*)d_in[9];
  const float* bo = (const float*)d_in[10];

  const size_t NE = (size_t)B_ * S_ * D_;  // 4,194,304
  ushort* Xbq = (ushort*)d_ws;
  ushort* Xbk = Xbq + NE;
  ushort* Xbv = Xbk + NE;
  ushort* Wtqkv = Xbv + NE;              // [3072][1024] bf16
  ushort* Wto = Wtqkv + 3 * 1024 * 1024;
  ushort* qtmp = Wto + 1024 * 1024;      // dense [4096][1024] bf16
  ushort* ktmp = qtmp + NE;
  ushort* vtmp = ktmp + NE;
  ushort* qfb = vtmp + NE;               // [bh][s][dk]
  ushort* kfb = qfb + NE;
  ushort* vtb = kfb + NE;                // [bh][dk][s]
  ushort* ctxb = qtmp;                   // alias: qtmp dead after rope_pass

  prep_all<<<7168, 256, 0, stream>>>(q_in, k_in, v_in, Xbq, Xbk, Xbv,
                                     Wq, Wk, Wv, Wo, Wtqkv, Wto);

  gemm_mfma<0><<<dim3(32, 24), 256, 0, stream>>>(
      Xbq, Xbk, Xbv, Wtqkv, bq, bk, bv, qtmp, ktmp, vtmp, nullptr);

  rope_pass<<<dim3(32, 32), 256, 0, stream>>>(qtmp, ktmp, vtmp, qfb, kfb, vtb);

  attn_mfma<<<dim3(32, 32), 128, 0, stream>>>(qfb, kfb, vtb, ctxb);

  gemm_mfma<2><<<dim3(32, 8), 256, 0, stream>>>(
      ctxb, ctxb, ctxb, Wto, bo, bo, bo, nullptr, nullptr, nullptr,
      (float*)d_out);
}

// Round 5
// 218.254 us; speedup vs baseline: 1.0932x; 1.0932x over previous
//
#include <hip/hip_runtime.h>
#include <hip/hip_bf16.h>
#include <math.h>

// (B,S,D,H) = (2,2048,1024,16), DK=64
#define B_ 2
#define S_ 2048
#define D_ 1024
#define H_ 16
#define DK_ 64

#define ROPE_C 0.4152410118609203f   // log2(10000)/32
#define LOG2E 1.4426950408889634f
#define QSCALE 0.18033688011112042f  // 0.125 * LOG2E (exp2-domain fold)

typedef float f4 __attribute__((ext_vector_type(4)));
typedef short s8 __attribute__((ext_vector_type(8)));

__device__ __forceinline__ ushort f2b(float f) {
  union { float f; uint u; } v; v.f = f;
  uint u = v.u + 0x7fffu + ((v.u >> 16) & 1u);
  return (ushort)(u >> 16);
}

__device__ __forceinline__ float b2f(ushort u) {
  union { uint u; float f; } v; v.u = ((uint)u) << 16;
  return v.f;
}

// packed f32x2 -> bf16x2 (T12: no builtin on gfx950; lo = src0)
__device__ __forceinline__ uint cvtpk(float a, float b) {
  uint r;
  asm("v_cvt_pk_bf16_f32 %0, %1, %2" : "=v"(r) : "v"(a), "v"(b));
  return r;
}

// async global->LDS DMA, 16 B per lane. LDS dest = wave-uniform base + lane*16.
__device__ __forceinline__ void async16(const ushort* g, ushort* l) {
  __builtin_amdgcn_global_load_lds(
      (const __attribute__((address_space(1))) uint*)g,
      (__attribute__((address_space(3))) uint*)l, 16, 0, 0);
}

// ---------------------------------------------------------------------------
// Fused prep: blocks 0..6143 = fp32->bf16 convert of q/k/v (8 elems/thread);
// blocks 6144..7167 = W transpose (4 matrices, 16x16 tiles of 64x64).
// ---------------------------------------------------------------------------
__global__ __launch_bounds__(256) void prep_all(
    const float* __restrict__ q_in, const float* __restrict__ k_in,
    const float* __restrict__ v_in,
    ushort* __restrict__ Xbq, ushort* __restrict__ Xbk, ushort* __restrict__ Xbv,
    const float* __restrict__ Wq, const float* __restrict__ Wk,
    const float* __restrict__ Wv, const float* __restrict__ Wo,
    ushort* __restrict__ Wtqkv, ushort* __restrict__ Wto) {
  __shared__ ushort T[64][65];
  const int bid = blockIdx.x, t = threadIdx.x;
  if (bid < 6144) {
    const int m = bid >> 11;  // /2048
    const float* in = (m == 0) ? q_in : (m == 1) ? k_in : v_in;
    ushort* out = (m == 0) ? Xbq : (m == 1) ? Xbk : Xbv;
    int idx = ((bid & 2047) * 256 + t) * 8;
    float4 a = *(const float4*)&in[idx];
    float4 b = *(const float4*)&in[idx + 4];
    ushort tmp[8] = {f2b(a.x), f2b(a.y), f2b(a.z), f2b(a.w),
                     f2b(b.x), f2b(b.y), f2b(b.z), f2b(b.w)};
    *(uint4*)&out[idx] = *(uint4*)tmp;
  } else {
    const int tb = bid - 6144;
    const int m = tb >> 8;
    const float* W = (m == 0) ? Wq : (m == 1) ? Wk : (m == 2) ? Wv : Wo;
    ushort* Wt = (m == 3) ? Wto : Wtqkv + (size_t)m * 1024 * 1024;
    const int k0 = (tb & 15) * 64, n0 = ((tb >> 4) & 15) * 64;
    #pragma unroll
    for (int i = 0; i < 16; ++i) {
      int e = t + i * 256, r = e >> 6, c = e & 63;
      T[c][r] = f2b(W[(size_t)(k0 + r) * D_ + n0 + c]);
    }
    __syncthreads();
    #pragma unroll
    for (int i = 0; i < 16; ++i) {
      int e = t + i * 256, r = e >> 6, c = e & 63;
      Wt[(size_t)(n0 + r) * D_ + k0 + c] = T[r][c];
    }
  }
}

// ---------------------------------------------------------------------------
// MFMA GEMM v3: BM=BN=128, BK=32, 4 waves 2x2, 4x4 frags/wave.
// Double-buffered global_load_lds staging, one barrier per K-step.
// MODE 0 (QKV projection): fused epilogue --
//   mat 0/1 (q/k): bias + RoPE (8 consecutive d per thread -> pairs are
//     thread-local) + q pre-scale, written DIRECTLY to [bh][s][dk] layout.
//   mat 2 (v): bias + transpose through LDS, written to [bh][dk][s].
//   Rounding path identical to the old separate rope_pass (bf16 after bias,
//   rope applied to bf16-rounded values).
// MODE 2: fp32 [M][N] + bias (final projection), direct stores.
// ---------------------------------------------------------------------------
template <int MODE>
__global__ __launch_bounds__(256) void gemm_mfma(
    const ushort* __restrict__ A0, const ushort* __restrict__ A1,
    const ushort* __restrict__ A2, const ushort* __restrict__ Bt,
    const float* __restrict__ bb0, const float* __restrict__ bb1,
    const float* __restrict__ bb2,
    ushort* __restrict__ oq, ushort* __restrict__ ok, ushort* __restrict__ ov,
    float* __restrict__ oo) {
  __shared__ ushort SM[16384];  // 32 KB: As[2][4096] | Bs[2][4096]
  ushort* Es = SM;              // MODE 0 epilogue scratch, aliases K-loop bufs

  const int t = threadIdx.x, w = t >> 6, l = t & 63;
  const int m0 = blockIdx.x * 128, n0 = blockIdx.y * 128;
  const int wm = (w >> 1) * 64, wn = (w & 1) * 64;
  const int lm = l & 15, q4 = (l >> 4) * 4;
  const int hb = l >> 4;

  const ushort* A;
  const float* bias;
  int mat = 0;
  if constexpr (MODE == 0) {
    mat = n0 >> 10;
    A = (mat == 0) ? A0 : (mat == 1) ? A1 : A2;
    bias = (mat == 0) ? bb0 : (mat == 1) ? bb1 : bb2;
  } else {
    A = A0; bias = bb0;
  }

  const int srow = w * 32 + (l >> 2);
  const int pb = l & 3;
  const int lb = pb ^ (srow & 3);
  const ushort* gA = A + (size_t)(m0 + srow) * D_ + lb * 8;
  const ushort* gB = Bt + (size_t)(n0 + srow) * D_ + lb * 8;

#define GSTAGE(bf, kk)                                   \
  {                                                      \
    ushort* lA = SM + (bf) * 4096 + w * 1024;            \
    ushort* lB = SM + 8192 + (bf) * 4096 + w * 1024;     \
    async16(gA + (kk), lA);                              \
    async16(gA + 16 * D_ + (kk), lA + 512);              \
    async16(gB + (kk), lB);                              \
    async16(gB + 16 * D_ + (kk), lB + 512);              \
  }

  f4 acc[4][4];
  #pragma unroll
  for (int i = 0; i < 4; ++i)
    #pragma unroll
    for (int j = 0; j < 4; ++j) acc[i][j] = (f4){0.f, 0.f, 0.f, 0.f};

  GSTAGE(0, 0);
  __syncthreads();

  for (int k0 = 0; k0 < D_; k0 += 32) {
    const int bf = (k0 >> 5) & 1;
    if (k0 + 32 < D_) GSTAGE(bf ^ 1, k0 + 32);
    const ushort* Asb = SM + bf * 4096;
    const ushort* Bsb = SM + 8192 + bf * 4096;
    s8 af[4], bfr[4];
    #pragma unroll
    for (int mt = 0; mt < 4; ++mt) {
      int ra = wm + mt * 16 + lm;
      af[mt] = *(const s8*)&Asb[ra * 32 + ((hb ^ (ra & 3)) << 3)];
    }
    #pragma unroll
    for (int nt = 0; nt < 4; ++nt) {
      int rb = wn + nt * 16 + lm;
      bfr[nt] = *(const s8*)&Bsb[rb * 32 + ((hb ^ (rb & 3)) << 3)];
    }
    __builtin_amdgcn_s_setprio(1);
    #pragma unroll
    for (int mt = 0; mt < 4; ++mt)
      #pragma unroll
      for (int nt = 0; nt < 4; ++nt)
        acc[mt][nt] = __builtin_amdgcn_mfma_f32_16x16x32_bf16(af[mt], bfr[nt], acc[mt][nt], 0, 0, 0);
    __builtin_amdgcn_s_setprio(0);
    __syncthreads();
  }

  // ---- epilogue ----
  if constexpr (MODE == 2) {
    #pragma unroll
    for (int nt = 0; nt < 4; ++nt) {
      int n = n0 + wn + nt * 16 + lm;
      float bv = bias[n];
      #pragma unroll
      for (int mt = 0; mt < 4; ++mt)
        #pragma unroll
        for (int r = 0; r < 4; ++r)
          oo[(size_t)(m0 + wm + mt * 16 + q4 + r) * D_ + n] = acc[mt][nt][r] + bv;
    }
  } else {
    const int nm0 = n0 & 1023;
    const int bI = m0 >> 11;  // batch (block never crosses the b boundary)
    if (mat < 2) {
      // ---- q/k: Es[64][144] per s-half; RoPE in store phase ----
      ushort* dst = (mat == 0) ? oq : ok;
      const float scale = (mat == 0) ? QSCALE : 1.f;
      #pragma unroll
      for (int p = 0; p < 2; ++p) {
        if ((w >> 1) == p) {
          #pragma unroll
          for (int nt = 0; nt < 4; ++nt) {
            int col = wn + nt * 16 + lm;
            float bv = bias[nm0 + col];
            #pragma unroll
            for (int mt = 0; mt < 4; ++mt)
              #pragma unroll
              for (int r = 0; r < 4; ++r)
                Es[(mt * 16 + q4 + r) * 144 + col] = f2b(acc[mt][nt][r] + bv);
          }
        }
        __syncthreads();
        #pragma unroll
        for (int i = 0; i < 4; ++i) {
          int e = t + i * 256, row = e >> 4, ch = e & 15;
          int sg = m0 + p * 64 + row;           // global s-row (b*S+s)
          int s = sg & 2047;
          int dcol = nm0 + ch * 8;              // d within D
          int hh = dcol >> 6, dk0 = dcol & 63;  // head, dk base (mult of 8)
          ushort xr[8];
          *(uint4*)xr = *(const uint4*)&Es[row * 144 + ch * 8];
          float x[8];
          #pragma unroll
          for (int j = 0; j < 8; ++j) x[j] = b2f(xr[j]);
          const float pos = (float)s;
          ushort o[8];
          #pragma unroll
          for (int j = 0; j < 8; j += 2) {
            int dg = dk0 + j;
            float inve = exp2f(-(float)(dg & 31) * ROPE_C);
            float invo = exp2f(-(float)((dg + 1) & 31) * ROPE_C);
            float se, ce, so, co;
            __sincosf(pos * inve, &se, &ce);
            __sincosf(pos * invo, &so, &co);
            float ev = x[j] * ce - x[j + 1] * so;
            float od = x[j] * se + x[j + 1] * co;
            o[j] = f2b(ev * scale);
            o[j + 1] = f2b(od * scale);
          }
          size_t didx = ((size_t)((bI * 16 + hh) * S_ + s)) * DK_ + dk0;
          *(uint4*)&dst[didx] = *(const uint4*)o;
        }
        __syncthreads();
      }
    } else {
      // ---- v: transpose through EsV[128][72]; store [bh][dk][s] ----
      #pragma unroll
      for (int p = 0; p < 2; ++p) {
        if ((w >> 1) == p) {
          #pragma unroll
          for (int nt = 0; nt < 4; ++nt) {
            int col = wn + nt * 16 + lm;
            float bv = bias[nm0 + col];
            #pragma unroll
            for (int mt = 0; mt < 4; ++mt)
              #pragma unroll
              for (int r = 0; r < 4; ++r)
                Es[col * 72 + (mt * 16 + q4 + r)] = f2b(acc[mt][nt][r] + bv);
          }
        }
        __syncthreads();
        #pragma unroll
        for (int i = 0; i < 4; ++i) {
          int e = t + i * 256, d = e >> 3, sc = e & 7;
          int dcol = nm0 + d;
          int hh = dcol >> 6, dkv = dcol & 63;
          int sg = m0 + p * 64 + sc * 8;
          int s = sg & 2047;
          size_t didx = ((size_t)((bI * 16 + hh) * DK_ + dkv)) * S_ + s;
          *(uint4*)&ov[didx] = *(const uint4*)&Es[d * 72 + sc * 8];
        }
        __syncthreads();
      }
    }
  }
#undef GSTAGE
}

// ---------------------------------------------------------------------------
// MFMA flash attention v4 (round-3 proven): prefetch + single-barrier K/V
// LDS pipeline, cvt_pk P-pack, XOR-swizzled unpadded Ps, exp2-domain,
// tree reductions, defer-max (THR=4), setprio MFMA.
// Grid (32 bh, 32 qt) LPT; 1024 blocks, 4 blocks/CU, 16 waves/CU.
// ---------------------------------------------------------------------------
__global__ __launch_bounds__(256, 4) void attn_mfma(const ushort* __restrict__ qf,
                                                    const ushort* __restrict__ kf,
                                                    const ushort* __restrict__ vtf,
                                                    ushort* __restrict__ ctx) {
  __shared__ ushort Ks[2][4096];   // [buf][64 rows][64] keys x dk, swizzled
  __shared__ ushort Vs[2][4096];   // [buf][64 rows][64] dk x keys, swizzled
  __shared__ ushort PsS[4096];     // [64][64] XOR-swizzled P scratch

  const int t = threadIdx.x, w = t >> 6, l = t & 63;
  const int bh = blockIdx.x, qt = 31 - (int)blockIdx.y;
  const int i0 = qt * 64;
  const int lm = l & 15, hb = l >> 4, h8 = hb * 8, q4 = hb * 4, w16 = w * 16;
  const size_t base = (size_t)bh * S_ * DK_;
  const int b = bh >> 4, h = bh & 15;

  // ---- staging geometry: one async16 covers 8 rows (8 lanes/row x 16B) ----
  const int sr = l >> 3, pbk = l & 7;
  const int swS = (pbk ^ sr) << 3;                    // pre-swizzled src block
  const ushort* gkA = kf + base + (size_t)(w * 16 + sr) * DK_ + swS;
  const ushort* gkB = kf + base + (size_t)(w * 16 + sr + 8) * DK_ + swS;
  const ushort* gvA = vtf + base + (size_t)(w * 16 + sr) * S_ + swS;
  const ushort* gvB = vtf + base + (size_t)(w * 16 + sr + 8) * S_ + swS;

#define STAGE(bf, j0)                                       \
  {                                                         \
    ushort* lk = &Ks[bf][w * 1024];                         \
    ushort* lv = &Vs[bf][w * 1024];                         \
    async16(gkA + (size_t)(j0) * DK_, lk);                  \
    async16(gkB + (size_t)(j0) * DK_, lk + 512);            \
    async16(gvA + (j0), lv);                                \
    async16(gvB + (j0), lv + 512);                          \
  }

  // ---- Q fragment: loop-invariant per wave (B-frag, col = q-row w16+lm) ----
  const ushort* qp = qf + base + (size_t)(i0 + w16 + lm) * DK_ + h8;
  const s8 bq0 = *(const s8*)qp;
  const s8 bq1 = *(const s8*)(qp + 32);

  // ---- read-side swizzle constants (row rr = nt*16+lm -> rr&7 = lm&7) ----
  const int swr = lm & 7;
  const int cA = (hb ^ swr) << 3;         // block hb   (cols h8..h8+7)
  const int cB = ((hb + 4) ^ swr) << 3;   // block hb+4 (cols 32+h8..)
  const int prow = (w16 + lm) * 64;

  STAGE(0, 0);

  f4 O[4];
  #pragma unroll
  for (int i = 0; i < 4; ++i) O[i] = (f4){0.f, 0.f, 0.f, 0.f};
  float m_ = -1e30f, l_ = 0.f;  // softmax state for q-row w16+lm (exp2 domain)

  __syncthreads();

  for (int jt = 0; jt <= qt; ++jt) {
    const int cur = jt & 1;
    if (jt < qt) STAGE(cur ^ 1, (jt + 1) * 64);   // prefetch next tile
    const ushort* Kb = Ks[cur];
    const ushort* Vb = Vs[cur];

    // ---- S^T = K @ Q^T ----
    f4 st[4];
    __builtin_amdgcn_s_setprio(1);
    #pragma unroll
    for (int nt = 0; nt < 4; ++nt) {
      const ushort* kRow = Kb + (nt * 16 + lm) * 64;
      s8 a0 = *(const s8*)&kRow[cA];
      s8 a1 = *(const s8*)&kRow[cB];
      f4 a = (f4){0.f, 0.f, 0.f, 0.f};
      a = __builtin_amdgcn_mfma_f32_16x16x32_bf16(a0, bq0, a, 0, 0, 0);
      a = __builtin_amdgcn_mfma_f32_16x16x32_bf16(a1, bq1, a, 0, 0, 0);
      st[nt] = a;
    }
    __builtin_amdgcn_s_setprio(0);

    if (jt == qt) {  // causal: key nt*16+q4+r vs qrow w16+lm
      #pragma unroll
      for (int nt = 0; nt < 4; ++nt)
        #pragma unroll
        for (int r = 0; r < 4; ++r)
          if (nt * 16 + q4 + r > w16 + lm) st[nt][r] = -1e30f;
    }

    // ---- row max: tree (depth 4) + 2 shfl ----
    float x0 = fmaxf(fmaxf(st[0][0], st[0][1]), fmaxf(st[0][2], st[0][3]));
    float x1 = fmaxf(fmaxf(st[1][0], st[1][1]), fmaxf(st[1][2], st[1][3]));
    float x2 = fmaxf(fmaxf(st[2][0], st[2][1]), fmaxf(st[2][2], st[2][3]));
    float x3 = fmaxf(fmaxf(st[3][0], st[3][1]), fmaxf(st[3][2], st[3][3]));
    float pm = fmaxf(fmaxf(x0, x1), fmaxf(x2, x3));
    pm = fmaxf(pm, __shfl_xor(pm, 16));
    pm = fmaxf(pm, __shfl_xor(pm, 32));

    // ---- defer-max (T13): skip rescale when max didn't grow past THR ----
    const bool stable = __all(pm <= m_ + 4.0f);
    float mn = m_, alpha = 1.f;
    if (!stable) {
      mn = fmaxf(m_, pm);
      alpha = exp2f(m_ - mn);
      m_ = mn;
    }

    // ---- exp (exp2 domain) + row sum: tree + 2 shfl ----
    #pragma unroll
    for (int nt = 0; nt < 4; ++nt)
      #pragma unroll
      for (int r = 0; r < 4; ++r)
        st[nt][r] = exp2f(st[nt][r] - mn);
    float s0 = (st[0][0] + st[0][1]) + (st[0][2] + st[0][3]);
    float s1 = (st[1][0] + st[1][1]) + (st[1][2] + st[1][3]);
    float s2 = (st[2][0] + st[2][1]) + (st[2][2] + st[2][3]);
    float s3 = (st[3][0] + st[3][1]) + (st[3][2] + st[3][3]);
    float ps = (s0 + s1) + (s2 + s3);
    ps += __shfl_xor(ps, 16);
    ps += __shfl_xor(ps, 32);

    if (stable) {
      l_ += ps;
    } else {
      l_ = l_ * alpha + ps;
      float ar[4];
      #pragma unroll
      for (int r = 0; r < 4; ++r) ar[r] = __shfl(alpha, q4 + r);
      #pragma unroll
      for (int nt = 0; nt < 4; ++nt)
        #pragma unroll
        for (int r = 0; r < 4; ++r) O[nt][r] *= ar[r];
    }

    // ---- P -> LDS, packed via cvt_pk, swizzled (same-wave rows, no bar) ----
    #pragma unroll
    for (int nt = 0; nt < 4; ++nt) {
      uint2 pp;
      pp.x = cvtpk(st[nt][0], st[nt][1]);
      pp.y = cvtpk(st[nt][2], st[nt][3]);
      const int pidx = prow + ((((nt << 1) + (hb >> 1)) ^ swr) << 3) + ((hb & 1) << 2);
      *(uint2*)&PsS[pidx] = pp;
    }
    s8 ap0 = *(const s8*)&PsS[prow + cA];
    s8 ap1 = *(const s8*)&PsS[prow + cB];

    // ---- PV ----
    __builtin_amdgcn_s_setprio(1);
    #pragma unroll
    for (int nt = 0; nt < 4; ++nt) {
      const ushort* vRow = Vb + (nt * 16 + lm) * 64;
      s8 v0 = *(const s8*)&vRow[cA];
      s8 v1 = *(const s8*)&vRow[cB];
      O[nt] = __builtin_amdgcn_mfma_f32_16x16x32_bf16(ap0, v0, O[nt], 0, 0, 0);
      O[nt] = __builtin_amdgcn_mfma_f32_16x16x32_bf16(ap1, v1, O[nt], 0, 0, 0);
    }
    __builtin_amdgcn_s_setprio(0);

    // single barrier: prefetched tile visible + buf reuse protected.
    __syncthreads();
  }

  // ---- epilogue: 1/l via shfl, transpose-stage in PsS (swizzled), store ----
  float il[4];
  #pragma unroll
  for (int r = 0; r < 4; ++r) il[r] = 1.f / __shfl(l_, q4 + r);
  #pragma unroll
  for (int nt = 0; nt < 4; ++nt)
    #pragma unroll
    for (int r = 0; r < 4; ++r) {
      int row = w16 + q4 + r, col = nt * 16 + lm;
      PsS[row * 64 + ((((col >> 3) ^ (row & 7)) << 3)) + (col & 7)] =
          f2b(O[nt][r] * il[r]);
    }
  __syncthreads();
  #pragma unroll
  for (int i = 0; i < 2; ++i) {
    int e = t + i * 256, row = e >> 3, ch = e & 7;
    int s = i0 + row;
    *(uint4*)&ctx[((size_t)(b * S_ + s)) * D_ + h * 64 + ch * 8] =
        *(const uint4*)&PsS[row * 64 + ((ch ^ (row & 7)) << 3)];
  }
#undef STAGE
}

// ---------------------------------------------------------------------------
extern "C" void kernel_launch(void* const* d_in, const int* in_sizes, int n_in,
                              void* d_out, int out_size, void* d_ws, size_t ws_size,
                              hipStream_t stream) {
  const float* q_in = (const float*)d_in[0];
  const float* k_in = (const float*)d_in[1];
  const float* v_in = (const float*)d_in[2];
  const float* Wq = (const float*)d_in[3];
  const float* bq = (const float*)d_in[4];
  const float* Wk = (const float*)d_in[5];
  const float* bk = (const float*)d_in[6];
  const float* Wv = (const float*)d_in[7];
  const float* bv = (const float*)d_in[8];
  const float* Wo = (const float*)d_in[9];
  const float* bo = (const float*)d_in[10];

  const size_t NE = (size_t)B_ * S_ * D_;  // 4,194,304
  ushort* Xbq = (ushort*)d_ws;
  ushort* Xbk = Xbq + NE;
  ushort* Xbv = Xbk + NE;
  ushort* Wtqkv = Xbv + NE;              // [3072][1024] bf16
  ushort* Wto = Wtqkv + 3 * 1024 * 1024;
  ushort* qfb = Wto + 1024 * 1024;       // [bh][s][dk] (rope'd, q pre-scaled)
  ushort* kfb = qfb + NE;                // [bh][s][dk] (rope'd)
  ushort* vtb = kfb + NE;                // [bh][dk][s]
  ushort* ctxb = vtb + NE;               // [b*S+s][D] attention context

  prep_all<<<7168, 256, 0, stream>>>(q_in, k_in, v_in, Xbq, Xbk, Xbv,
                                     Wq, Wk, Wv, Wo, Wtqkv, Wto);

  // QKV projection with fused bias + RoPE + head-relayout epilogue
  gemm_mfma<0><<<dim3(32, 24), 256, 0, stream>>>(
      Xbq, Xbk, Xbv, Wtqkv, bq, bk, bv, qfb, kfb, vtb, nullptr);

  attn_mfma<<<dim3(32, 32), 256, 0, stream>>>(qfb, kfb, vtb, ctxb);

  gemm_mfma<2><<<dim3(32, 8), 256, 0, stream>>>(
      ctxb, ctxb, ctxb, Wto, bo, bo, bo, nullptr, nullptr, nullptr,
      (float*)d_out);
}